// Round 1
// baseline (519.427 us; speedup 1.0000x reference)
//
#include <hip/hip_runtime.h>
#include <math.h>

// Problem constants (fixed by reference file)
#define B_DIM    16
#define D_DIM    1024
#define K_FREQ   64          // frequencies; 2K = 128 features
#define F_DIM    128
#define N_MAXLEN 8192

// GEMM tile config
#define BM   128
#define BN   128
#define LDSS 136             // LDS row stride in bf16 elems (128 + 8 pad -> conflict-free-ish)

typedef __attribute__((ext_vector_type(8))) short bf16x8;   // 8 bf16 in 4 VGPRs (MFMA A/B frag)
typedef __attribute__((ext_vector_type(4))) float f32x4;    // MFMA C/D frag

__device__ __forceinline__ unsigned short f2bf(float x) {
    union { float f; unsigned u; } v; v.f = x;
    unsigned r = (v.u + 0x7FFFu + ((v.u >> 16) & 1u)) >> 16;  // RNE
    return (unsigned short)r;
}

// out[m, d] = sum_f feats[m, f] * W[d, f]
// feats[m, 2k]   = cos(2*pi*n*(k+1)/len_b) / 8     (m = b*8192 + n, masked to 0 if n >= len_b)
// feats[m, 2k+1] = sin(...) / 8
__global__ __launch_bounds__(256, 2) void cyclic_gemm_kernel(
    const int* __restrict__ lengths,
    const float* __restrict__ W,      // [D_DIM][F_DIM] fp32 row-major
    float* __restrict__ out)          // [B*N][D_DIM] fp32
{
    __shared__ short sA[BM * LDSS];   // feats tile, bf16
    __shared__ short sB[BN * LDSS];   // W tile, bf16 (same [d][f] layout as global)

    const int tid = threadIdx.x;
    const int m0  = blockIdx.y * BM;
    const int d0  = blockIdx.x * BN;

    // ---- Fill sA: two threads per row, 32 (cos,sin) pairs each ----
    {
        const int r    = tid >> 1;        // 0..127
        const int half = tid & 1;         // which half of the 64 freqs
        const int m    = m0 + r;
        const int b    = m >> 13;         // /8192
        const int n    = m & (N_MAXLEN - 1);
        const int len  = lengths[b];
        unsigned* dst = (unsigned*)&sA[r * LDSS + half * 64];  // 32 packed (cos,sin) dwords
        if (n >= len) {
            #pragma unroll
            for (int j = 0; j < 32; ++j) dst[j] = 0u;
        } else {
            const float base = (float)n / (float)len;   // revolutions per unit freq
            #pragma unroll
            for (int j = 0; j < 32; ++j) {
                const int k = half * 32 + j;            // freq index 0..63 -> (k+1)
                float rev = base * (float)(k + 1);
                rev -= floorf(rev);                     // range-reduce to [0,1)
                float s, c;
                __sincosf(6.283185307179586f * rev, &s, &c);
                const unsigned cb = f2bf(c * 0.125f);
                const unsigned sb = f2bf(s * 0.125f);
                dst[j] = cb | (sb << 16);               // interleaved [cos, sin]
            }
        }
    }

    // ---- Fill sB: W[d0..d0+127][0..127] fp32 -> bf16, float4 coalesced loads ----
    {
        const float4* Wv = (const float4*)(W + (size_t)d0 * F_DIM);
        #pragma unroll
        for (int i = 0; i < 16; ++i) {
            const int lin = tid + i * 256;      // 0..4095 float4 slots
            const int row = lin >> 5;           // 32 float4 per 128-wide row
            const int c4  = lin & 31;
            const float4 w = Wv[row * 32 + c4];
            unsigned* p = (unsigned*)&sB[row * LDSS + c4 * 4];
            p[0] = (unsigned)f2bf(w.x) | ((unsigned)f2bf(w.y) << 16);
            p[1] = (unsigned)f2bf(w.z) | ((unsigned)f2bf(w.w) << 16);
        }
    }

    __syncthreads();

    // ---- MFMA: 4 waves in 2x2, each computes 64x64 ----
    const int lane = tid & 63;
    const int wave = tid >> 6;
    const int wm   = (wave >> 1) * 64;
    const int wn   = (wave & 1) * 64;
    const int lrow = lane & 15;
    const int quad = lane >> 4;

    f32x4 acc[4][4];
    #pragma unroll
    for (int mi = 0; mi < 4; ++mi)
        #pragma unroll
        for (int ni = 0; ni < 4; ++ni)
            acc[mi][ni] = (f32x4){0.f, 0.f, 0.f, 0.f};

    // A frag: A[m = lrow][k = quad*8 + j] ; B frag: B[k = quad*8 + j][col = lrow]
    // Both tiles are [row][k] so both frags use the identical addressing pattern.
    const short* aBase = &sA[(wm + lrow) * LDSS + quad * 8];
    const short* bBase = &sB[(wn + lrow) * LDSS + quad * 8];

    #pragma unroll
    for (int ks = 0; ks < 4; ++ks) {            // K = 128 in 4 steps of 32
        bf16x8 af[4], bfr[4];
        #pragma unroll
        for (int i = 0; i < 4; ++i) {
            af[i]  = *(const bf16x8*)(aBase + i * 16 * LDSS + ks * 32);
            bfr[i] = *(const bf16x8*)(bBase + i * 16 * LDSS + ks * 32);
        }
        #pragma unroll
        for (int mi = 0; mi < 4; ++mi)
            #pragma unroll
            for (int ni = 0; ni < 4; ++ni)
                acc[mi][ni] = __builtin_amdgcn_mfma_f32_16x16x32_bf16(
                    af[mi], bfr[ni], acc[mi][ni], 0, 0, 0);
    }

    // ---- Epilogue: C/D layout col = lane&15, row = quad*4 + reg ----
    #pragma unroll
    for (int mi = 0; mi < 4; ++mi) {
        #pragma unroll
        for (int reg = 0; reg < 4; ++reg) {
            const int row = m0 + wm + mi * 16 + quad * 4 + reg;
            float* orow = out + (size_t)row * D_DIM + (d0 + wn + lrow);
            #pragma unroll
            for (int ni = 0; ni < 4; ++ni)
                orow[ni * 16] = acc[mi][ni][reg];
        }
    }
}

__global__ void mask_kernel(const int* __restrict__ lengths, float* __restrict__ maskp) {
    const int i = blockIdx.x * blockDim.x + threadIdx.x;   // 0 .. B*N-1
    const int b = i >> 13;
    const int n = i & (N_MAXLEN - 1);
    maskp[i] = (n < lengths[b]) ? 1.0f : 0.0f;
}

extern "C" void kernel_launch(void* const* d_in, const int* in_sizes, int n_in,
                              void* d_out, int out_size, void* d_ws, size_t ws_size,
                              hipStream_t stream) {
    const int*   lengths = (const int*)d_in[0];
    const float* W       = (const float*)d_in[1];
    // d_in[2] is N_max (== 8192), compile-time constant here.
    float* out   = (float*)d_out;
    float* maskp = out + (size_t)B_DIM * N_MAXLEN * D_DIM;

    dim3 grid(D_DIM / BN, (B_DIM * N_MAXLEN) / BM);   // (8, 1024)
    cyclic_gemm_kernel<<<grid, dim3(256), 0, stream>>>(lengths, W, out);

    const int mtot = B_DIM * N_MAXLEN;
    mask_kernel<<<mtot / 256, dim3(256), 0, stream>>>(lengths, maskp);
}